// Round 2
// baseline (4806.058 us; speedup 1.0000x reference)
//
#include <hip/hip_runtime.h>

using f4_t  = __attribute__((ext_vector_type(4))) float;
using bf8_t = __attribute__((ext_vector_type(8))) short;
using u32x4 = __attribute__((ext_vector_type(4))) unsigned int;

#define T_DIM 512
#define B_DIM 256
#define I_DIM 256
#define H_DIM 1024
#define O_DIM 128

// XOR swizzle: spread 16B slots of a row across banks (T2 recipe)
#define SWZ(row, byte) ((byte) ^ (((row) & 7) << 4))

__device__ __forceinline__ unsigned short f2bf(float f) {
  unsigned u = __builtin_bit_cast(unsigned, f);
  return (unsigned short)((u + 0x7FFFu + ((u >> 16) & 1u)) >> 16);
}

__device__ __forceinline__ unsigned long long pack4bf(f4_t v) {
  unsigned long long r;
  r  = (unsigned long long)f2bf(v[0]);
  r |= (unsigned long long)f2bf(v[1]) << 16;
  r |= (unsigned long long)f2bf(v[2]) << 32;
  r |= (unsigned long long)f2bf(v[3]) << 48;
  return r;
}

// ---------------------------------------------------------------- init ------
__global__ __launch_bounds__(256, 1) void k_init(
    const float* __restrict__ Wi, const float* __restrict__ Wh,
    const float* __restrict__ Wo, unsigned short* __restrict__ Wi_b,
    unsigned short* __restrict__ Wh_b, unsigned short* __restrict__ Wo_b,
    unsigned short* __restrict__ hbuf1, unsigned* __restrict__ done) {
  int idx = blockIdx.x * 256 + threadIdx.x;
  int stride = gridDim.x * 256;
  for (int i = idx; i < H_DIM * H_DIM; i += stride) Wh_b[i] = f2bf(Wh[i]);
  for (int i = idx; i < H_DIM * I_DIM; i += stride) Wi_b[i] = f2bf(Wi[i]);
  for (int i = idx; i < O_DIM * H_DIM; i += stride) Wo_b[i] = f2bf(Wo[i]);
  for (int i = idx; i < B_DIM * H_DIM; i += stride) hbuf1[i] = 0;
  for (int i = idx; i < 256 * 32; i += stride) done[i] = 0;
}

// --------------------------------------------------- phase 1: x @ Wi^T + bi -
// M=131072 (t*b), N=1024 (h), K=256.  128x128 tile, BK=128, 4 waves (64x64),
// XCD-swizzled so the 8 same-mb blocks share one XCD's L2 (x read once).
__global__ __launch_bounds__(256, 2) void k_inproj(
    const float* __restrict__ x, const unsigned short* __restrict__ Wi_b,
    const float* __restrict__ bi, float* __restrict__ act) {
  __shared__ unsigned short As[128 * 128];
  __shared__ unsigned short Bs[128 * 128];
  int blk = blockIdx.x;
  int mb = (blk & 7) * 128 + (blk >> 6);
  int nb = (blk >> 3) & 7;
  int m0 = mb * 128, n0 = nb * 128;
  int tid = threadIdx.x;
  int lane = tid & 63, w = tid >> 6;
  int wm0 = (w & 1) * 64, wn0 = (w >> 1) * 64;
  int lrow = lane & 15, lk = (lane >> 4) * 8;
  f4_t acc[4][4];
#pragma unroll
  for (int a = 0; a < 4; ++a)
#pragma unroll
    for (int b = 0; b < 4; ++b) acc[a][b] = (f4_t){0.f, 0.f, 0.f, 0.f};

  for (int kb = 0; kb < 2; ++kb) {
    if (kb) __syncthreads();
    // stage A (fp32 -> bf16), 128 rows x 128 k
#pragma unroll
    for (int it = 0; it < 16; ++it) {
      int c = it * 256 + tid;
      int row = c >> 5;
      int kc = (c & 31) * 4;
      f4_t v = *(const f4_t*)(x + (size_t)(m0 + row) * I_DIM + kb * 128 + kc);
      *(unsigned long long*)((char*)As + SWZ(row, row * 256 + kc * 2)) = pack4bf(v);
    }
    // stage B (already bf16), 128 rows x 128 k
#pragma unroll
    for (int it = 0; it < 8; ++it) {
      int c = it * 256 + tid;
      int row = c >> 4;
      int k16 = c & 15;
      u32x4 v = *(const u32x4*)(Wi_b + (size_t)(n0 + row) * I_DIM + kb * 128 + k16 * 8);
      *(u32x4*)((char*)Bs + SWZ(row, row * 256 + k16 * 16)) = v;
    }
    __syncthreads();
#pragma unroll
    for (int ks = 0; ks < 4; ++ks) {
      bf8_t aF[4], bF[4];
#pragma unroll
      for (int mt = 0; mt < 4; ++mt) {
        int row = wm0 + mt * 16 + lrow;
        aF[mt] = *(const bf8_t*)((char*)As + SWZ(row, row * 256 + (ks * 32 + lk) * 2));
      }
#pragma unroll
      for (int nt = 0; nt < 4; ++nt) {
        int row = wn0 + nt * 16 + lrow;
        bF[nt] = *(const bf8_t*)((char*)Bs + SWZ(row, row * 256 + (ks * 32 + lk) * 2));
      }
#pragma unroll
      for (int mt = 0; mt < 4; ++mt)
#pragma unroll
        for (int nt = 0; nt < 4; ++nt)
          acc[mt][nt] =
              __builtin_amdgcn_mfma_f32_16x16x32_bf16(aF[mt], bF[nt], acc[mt][nt], 0, 0, 0);
    }
  }
#pragma unroll
  for (int nt = 0; nt < 4; ++nt) {
    int col = n0 + wn0 + nt * 16 + lrow;
    float bv = bi[col];
#pragma unroll
    for (int mt = 0; mt < 4; ++mt) {
      int rbase = m0 + wm0 + mt * 16 + (lane >> 4) * 4;
#pragma unroll
      for (int r = 0; r < 4; ++r)
        act[(size_t)(rbase + r) * H_DIM + col] = acc[mt][nt][r] + bv;
    }
  }
}

// ------------------------------------------------------- phase 2: the scan --
// 16 independent B-groups (16 batch rows each) x 16 h-slice WGs.
// WG output: 16b x 64h.  4 waves split K (256 each); Wh B-fragments live in
// VGPRs for all 512 steps.  Cross-WG h exchange: agent-scope relaxed atomics
// (cache-bypassing); per-WG "done" slot (release) + per-lane spin (relaxed).
__global__ __launch_bounds__(256, 1) void k_scan(
    const unsigned short* __restrict__ Wh_b, const float* __restrict__ bh,
    float* __restrict__ act, unsigned short* __restrict__ hbuf0,
    unsigned short* __restrict__ hbuf1, unsigned* __restrict__ done) {
  __shared__ float pbuf[4][16][64];
  int blk = blockIdx.x;
  int g = blk & 15, hs = blk >> 4;   // group g's 16 WGs all land on XCD g%8
  int b0 = g * 16, h0 = hs * 64;
  int tid = threadIdx.x;
  int lane = tid & 63, w = tid >> 6;
  int lrow = lane & 15, lk = (lane >> 4) * 8;

  // persistent Wh fragments: [n-tile][k-chunk], K-slice = w*256..w*256+255
  bf8_t Bf[4][8];
#pragma unroll
  for (int n = 0; n < 4; ++n)
#pragma unroll
    for (int kc = 0; kc < 8; ++kc)
      Bf[n][kc] = *(const bf8_t*)(Wh_b + (size_t)(h0 + n * 16 + lrow) * H_DIM +
                                  w * 256 + kc * 32 + lk);

  int pr = tid >> 4, pc = (tid & 15) * 4;  // pointwise ownership: row pr, cols pc..pc+3
  float st[4] = {0.f, 0.f, 0.f, 0.f};
  float bh4[4];
#pragma unroll
  for (int j = 0; j < 4; ++j) bh4[j] = bh[h0 + pc + j];

  unsigned short* hb[2] = {hbuf0, hbuf1};
  unsigned* myslot = done + (g * 16 + hs) * 32;
  const unsigned* waitslot = done + (g * 16 + (tid & 15)) * 32;

  for (int t = 0; t < T_DIM; ++t) {
    if (t > 0 && tid < 64) {
      int guard = 0;
      while (__hip_atomic_load(waitslot, __ATOMIC_RELAXED, __HIP_MEMORY_SCOPE_AGENT) <
                 (unsigned)t &&
             ++guard < 500000)
        __builtin_amdgcn_s_sleep(2);
    }
    __syncthreads();

    const unsigned short* hprev = hb[(t + 1) & 1];
    bf8_t Af[8];
#pragma unroll
    for (int kc = 0; kc < 8; ++kc) {
      const unsigned long long* ap =
          (const unsigned long long*)(hprev + (size_t)(b0 + lrow) * H_DIM + w * 256 +
                                      kc * 32 + lk);
      unsigned long long lo = __hip_atomic_load(ap, __ATOMIC_RELAXED, __HIP_MEMORY_SCOPE_AGENT);
      unsigned long long hi =
          __hip_atomic_load(ap + 1, __ATOMIC_RELAXED, __HIP_MEMORY_SCOPE_AGENT);
      union { unsigned long long q[2]; bf8_t v; } uu;
      uu.q[0] = lo;
      uu.q[1] = hi;
      Af[kc] = uu.v;
    }
    f4_t acc[4];
#pragma unroll
    for (int n = 0; n < 4; ++n) acc[n] = (f4_t){0.f, 0.f, 0.f, 0.f};
#pragma unroll
    for (int kc = 0; kc < 8; ++kc)
#pragma unroll
      for (int n = 0; n < 4; ++n)
        acc[n] = __builtin_amdgcn_mfma_f32_16x16x32_bf16(Af[kc], Bf[n][kc], acc[n], 0, 0, 0);

    // cross-wave K reduction via LDS
#pragma unroll
    for (int n = 0; n < 4; ++n)
#pragma unroll
      for (int r = 0; r < 4; ++r)
        pbuf[w][(lane >> 4) * 4 + r][n * 16 + lrow] = acc[n][r];
    __syncthreads();

    // pointwise: sum partials + u_t + bh, leaky update, relu
    float* arow = act + ((size_t)t * B_DIM + b0 + pr) * H_DIM + h0 + pc;
    f4_t uvec = *(const f4_t*)arow;
    f4_t hres;
#pragma unroll
    for (int j = 0; j < 4; ++j) {
      float tot = pbuf[0][pr][pc + j] + pbuf[1][pr][pc + j] + pbuf[2][pr][pc + j] +
                  pbuf[3][pr][pc + j] + uvec[j] + bh4[j];
      st[j] = st[j] * 0.8f + tot * 0.2f;
      hres[j] = fmaxf(st[j], 0.f);
    }
    *(f4_t*)arow = hres;  // rnn_activity (fp32, in place over inp_proj)
    unsigned long long hp = pack4bf(hres);
    __hip_atomic_store(
        (unsigned long long*)(hb[t & 1] + ((size_t)(b0 + pr)) * H_DIM + h0 + pc), hp,
        __ATOMIC_RELAXED, __HIP_MEMORY_SCOPE_AGENT);

    __syncthreads();  // drains each thread's stores (vmcnt 0) before flagging
    if (tid == 0)
      __hip_atomic_store(myslot, (unsigned)(t + 1), __ATOMIC_RELEASE,
                         __HIP_MEMORY_SCOPE_AGENT);
  }
}

// ------------------------------------------------- phase 3: act @ Wo^T + bo -
// M=131072, N=128 (=O, one block covers all), K=1024, BK=64, 16 K-iters.
__global__ __launch_bounds__(256, 2) void k_outproj(
    const float* __restrict__ act, const unsigned short* __restrict__ Wo_b,
    const float* __restrict__ bo, float* __restrict__ out) {
  __shared__ unsigned short As[128 * 64];
  __shared__ unsigned short Bs[128 * 64];
  int m0 = blockIdx.x * 128;
  int tid = threadIdx.x;
  int lane = tid & 63, w = tid >> 6;
  int wm0 = (w & 1) * 64, wn0 = (w >> 1) * 64;
  int lrow = lane & 15, lk = (lane >> 4) * 8;
  f4_t acc[4][4];
#pragma unroll
  for (int a = 0; a < 4; ++a)
#pragma unroll
    for (int b = 0; b < 4; ++b) acc[a][b] = (f4_t){0.f, 0.f, 0.f, 0.f};

  for (int kb = 0; kb < 16; ++kb) {
    if (kb) __syncthreads();
#pragma unroll
    for (int it = 0; it < 8; ++it) {
      int c = it * 256 + tid;
      int row = c >> 4;
      int kc = (c & 15) * 4;
      f4_t v = *(const f4_t*)(act + (size_t)(m0 + row) * H_DIM + kb * 64 + kc);
      *(unsigned long long*)((char*)As + SWZ(row, row * 128 + kc * 2)) = pack4bf(v);
    }
    // Bs: 128 rows x 64 k = 8192 bf16 -> 4 its x 256 thr x 8 bf16  (R1 fix:
    // was 2 its / half-row coverage -> ks=1 MFMA pass read uninitialized LDS)
#pragma unroll
    for (int it = 0; it < 4; ++it) {
      int c = it * 256 + tid;
      int row = c >> 3;
      int k16 = c & 7;
      u32x4 v = *(const u32x4*)(Wo_b + (size_t)row * H_DIM + kb * 64 + k16 * 8);
      *(u32x4*)((char*)Bs + SWZ(row, row * 128 + k16 * 16)) = v;
    }
    __syncthreads();
#pragma unroll
    for (int ks = 0; ks < 2; ++ks) {
      bf8_t aF[4], bF[4];
#pragma unroll
      for (int mt = 0; mt < 4; ++mt) {
        int row = wm0 + mt * 16 + lrow;
        aF[mt] = *(const bf8_t*)((char*)As + SWZ(row, row * 128 + (ks * 32 + lk) * 2));
      }
#pragma unroll
      for (int nt = 0; nt < 4; ++nt) {
        int row = wn0 + nt * 16 + lrow;
        bF[nt] = *(const bf8_t*)((char*)Bs + SWZ(row, row * 128 + (ks * 32 + lk) * 2));
      }
#pragma unroll
      for (int mt = 0; mt < 4; ++mt)
#pragma unroll
        for (int nt = 0; nt < 4; ++nt)
          acc[mt][nt] =
              __builtin_amdgcn_mfma_f32_16x16x32_bf16(aF[mt], bF[nt], acc[mt][nt], 0, 0, 0);
    }
  }
#pragma unroll
  for (int nt = 0; nt < 4; ++nt) {
    int col = wn0 + nt * 16 + lrow;
    float bv = bo[col];
#pragma unroll
    for (int mt = 0; mt < 4; ++mt) {
      int rbase = m0 + wm0 + mt * 16 + (lane >> 4) * 4;
#pragma unroll
      for (int r = 0; r < 4; ++r)
        out[(size_t)(rbase + r) * O_DIM + col] = acc[mt][nt][r] + bv;
    }
  }
}

// ---------------------------------------------------------------------------
extern "C" void kernel_launch(void* const* d_in, const int* in_sizes, int n_in,
                              void* d_out, int out_size, void* d_ws, size_t ws_size,
                              hipStream_t stream) {
  const float* x  = (const float*)d_in[0];
  const float* Wi = (const float*)d_in[1];
  const float* bi = (const float*)d_in[2];
  const float* Wh = (const float*)d_in[3];
  const float* bh = (const float*)d_in[4];
  const float* Wo = (const float*)d_in[5];
  const float* bo = (const float*)d_in[6];

  float* out = (float*)d_out;                                  // [T,B,O]
  float* act = out + (size_t)T_DIM * B_DIM * O_DIM;            // [T,B,H]

  char* ws = (char*)d_ws;
  unsigned short* Wh_b  = (unsigned short*)(ws);                               // 2 MB
  unsigned short* Wi_b  = (unsigned short*)(ws + (2u << 20));                  // 512 KB
  unsigned short* Wo_b  = (unsigned short*)(ws + (2u << 20) + (512u << 10));   // 256 KB
  unsigned short* hbuf0 = (unsigned short*)(ws + (2u << 20) + (768u << 10));   // 512 KB
  unsigned short* hbuf1 = (unsigned short*)(ws + (2u << 20) + (1280u << 10));  // 512 KB
  unsigned* done        = (unsigned*)(ws + (2u << 20) + (1792u << 10));        // 32 KB

  k_init<<<1024, 256, 0, stream>>>(Wi, Wh, Wo, Wi_b, Wh_b, Wo_b, hbuf1, done);
  k_inproj<<<8192, 256, 0, stream>>>(x, Wi_b, bi, act);
  k_scan<<<256, 256, 0, stream>>>(Wh_b, bh, act, hbuf0, hbuf1, done);
  k_outproj<<<1024, 256, 0, stream>>>(act, Wo_b, bo, out);
}

// Round 3
// 2340.395 us; speedup vs baseline: 2.0535x; 2.0535x over previous
//
#include <hip/hip_runtime.h>

using f4_t  = __attribute__((ext_vector_type(4))) float;
using bf8_t = __attribute__((ext_vector_type(8))) short;
using u32x4 = __attribute__((ext_vector_type(4))) unsigned int;

#define T_DIM 512
#define B_DIM 256
#define I_DIM 256
#define H_DIM 1024
#define O_DIM 128

// XOR swizzle: spread 16B slots of a row across banks (T2 recipe)
#define SWZ(row, byte) ((byte) ^ (((row) & 7) << 4))

__device__ __forceinline__ unsigned short f2bf(float f) {
  unsigned u = __builtin_bit_cast(unsigned, f);
  return (unsigned short)((u + 0x7FFFu + ((u >> 16) & 1u)) >> 16);
}

__device__ __forceinline__ unsigned long long pack4bf(f4_t v) {
  unsigned long long r;
  r  = (unsigned long long)f2bf(v[0]);
  r |= (unsigned long long)f2bf(v[1]) << 16;
  r |= (unsigned long long)f2bf(v[2]) << 32;
  r |= (unsigned long long)f2bf(v[3]) << 48;
  return r;
}

// ---------------------------------------------------------------- init ------
__global__ __launch_bounds__(256, 1) void k_init(
    const float* __restrict__ Wi, const float* __restrict__ Wh,
    const float* __restrict__ Wo, unsigned short* __restrict__ Wi_b,
    unsigned short* __restrict__ Wh_b, unsigned short* __restrict__ Wo_b,
    unsigned short* __restrict__ hbuf1, unsigned* __restrict__ done) {
  int idx = blockIdx.x * 256 + threadIdx.x;
  int stride = gridDim.x * 256;
  for (int i = idx; i < H_DIM * H_DIM; i += stride) Wh_b[i] = f2bf(Wh[i]);
  for (int i = idx; i < H_DIM * I_DIM; i += stride) Wi_b[i] = f2bf(Wi[i]);
  for (int i = idx; i < O_DIM * H_DIM; i += stride) Wo_b[i] = f2bf(Wo[i]);
  for (int i = idx; i < B_DIM * H_DIM; i += stride) hbuf1[i] = 0;
  for (int i = idx; i < 256 * 32; i += stride) done[i] = 0;
}

// --------------------------------------------------- phase 1: x @ Wi^T + bi -
__global__ __launch_bounds__(256, 2) void k_inproj(
    const float* __restrict__ x, const unsigned short* __restrict__ Wi_b,
    const float* __restrict__ bi, float* __restrict__ act) {
  __shared__ unsigned short As[128 * 128];
  __shared__ unsigned short Bs[128 * 128];
  int blk = blockIdx.x;
  int mb = (blk & 7) * 128 + (blk >> 6);
  int nb = (blk >> 3) & 7;
  int m0 = mb * 128, n0 = nb * 128;
  int tid = threadIdx.x;
  int lane = tid & 63, w = tid >> 6;
  int wm0 = (w & 1) * 64, wn0 = (w >> 1) * 64;
  int lrow = lane & 15, lk = (lane >> 4) * 8;
  f4_t acc[4][4];
#pragma unroll
  for (int a = 0; a < 4; ++a)
#pragma unroll
    for (int b = 0; b < 4; ++b) acc[a][b] = (f4_t){0.f, 0.f, 0.f, 0.f};

  for (int kb = 0; kb < 2; ++kb) {
    if (kb) __syncthreads();
#pragma unroll
    for (int it = 0; it < 16; ++it) {
      int c = it * 256 + tid;
      int row = c >> 5;
      int kc = (c & 31) * 4;
      f4_t v = *(const f4_t*)(x + (size_t)(m0 + row) * I_DIM + kb * 128 + kc);
      *(unsigned long long*)((char*)As + SWZ(row, row * 256 + kc * 2)) = pack4bf(v);
    }
#pragma unroll
    for (int it = 0; it < 8; ++it) {
      int c = it * 256 + tid;
      int row = c >> 4;
      int k16 = c & 15;
      u32x4 v = *(const u32x4*)(Wi_b + (size_t)(n0 + row) * I_DIM + kb * 128 + k16 * 8);
      *(u32x4*)((char*)Bs + SWZ(row, row * 256 + k16 * 16)) = v;
    }
    __syncthreads();
#pragma unroll
    for (int ks = 0; ks < 4; ++ks) {
      bf8_t aF[4], bF[4];
#pragma unroll
      for (int mt = 0; mt < 4; ++mt) {
        int row = wm0 + mt * 16 + lrow;
        aF[mt] = *(const bf8_t*)((char*)As + SWZ(row, row * 256 + (ks * 32 + lk) * 2));
      }
#pragma unroll
      for (int nt = 0; nt < 4; ++nt) {
        int row = wn0 + nt * 16 + lrow;
        bF[nt] = *(const bf8_t*)((char*)Bs + SWZ(row, row * 256 + (ks * 32 + lk) * 2));
      }
#pragma unroll
      for (int mt = 0; mt < 4; ++mt)
#pragma unroll
        for (int nt = 0; nt < 4; ++nt)
          acc[mt][nt] =
              __builtin_amdgcn_mfma_f32_16x16x32_bf16(aF[mt], bF[nt], acc[mt][nt], 0, 0, 0);
    }
  }
#pragma unroll
  for (int nt = 0; nt < 4; ++nt) {
    int col = n0 + wn0 + nt * 16 + lrow;
    float bv = bi[col];
#pragma unroll
    for (int mt = 0; mt < 4; ++mt) {
      int rbase = m0 + wm0 + mt * 16 + (lane >> 4) * 4;
#pragma unroll
      for (int r = 0; r < 4; ++r)
        act[(size_t)(rbase + r) * H_DIM + col] = acc[mt][nt][r] + bv;
    }
  }
}

// ------------------------------------------------------- phase 2: the scan --
// R2 changes (fence/latency surgery):
//  - flag store is RELAXED (manual release: pre-barrier vmcnt(0) drain acks the
//    sc1 data stores at IC) -> no per-step L2 writeback flush from RELEASE
//  - spin skips OWN slot (was a full IC round trip per step)
//  - u_t prefetched one step ahead (plain cached load, off critical path)
//  - all waves spin -> 2 barriers/step instead of 3
__global__ __launch_bounds__(256, 1) void k_scan(
    const unsigned short* __restrict__ Wh_b, const float* __restrict__ bh,
    float* __restrict__ act, unsigned short* __restrict__ hbuf0,
    unsigned short* __restrict__ hbuf1, unsigned* __restrict__ done) {
  __shared__ float pbuf[4][16][64];
  int blk = blockIdx.x;
  int g = blk & 15, hs = blk >> 4;   // group g's WGs: blk = g + 16*hs
  int b0 = g * 16, h0 = hs * 64;
  int tid = threadIdx.x;
  int lane = tid & 63, w = tid >> 6;
  int lrow = lane & 15, lk = (lane >> 4) * 8;

  // persistent Wh fragments: [n-tile][k-chunk], K-slice = w*256..w*256+255
  bf8_t Bf[4][8];
#pragma unroll
  for (int n = 0; n < 4; ++n)
#pragma unroll
    for (int kc = 0; kc < 8; ++kc)
      Bf[n][kc] = *(const bf8_t*)(Wh_b + (size_t)(h0 + n * 16 + lrow) * H_DIM +
                                  w * 256 + kc * 32 + lk);

  int pr = tid >> 4, pc = (tid & 15) * 4;  // pointwise ownership
  float st[4] = {0.f, 0.f, 0.f, 0.f};
  float bh4[4];
#pragma unroll
  for (int j = 0; j < 4; ++j) bh4[j] = bh[h0 + pc + j];

  unsigned short* hb[2] = {hbuf0, hbuf1};
  unsigned* myslot = done + (g * 16 + hs) * 32;
  const unsigned* mywait = done + (g * 16 + (lane & 15)) * 32;

  // prefetch u for t=0
  f4_t ucur = *(const f4_t*)(act + ((size_t)0 * B_DIM + b0 + pr) * H_DIM + h0 + pc);

  for (int t = 0; t < T_DIM; ++t) {
    // spin: every wave's lanes 0..15 poll the 16 partner slots, skipping our own
    if (t > 0 && lane < 16 && lane != hs) {
      int guard = 0;
      while (__hip_atomic_load(mywait, __ATOMIC_RELAXED, __HIP_MEMORY_SCOPE_AGENT) <
                 (unsigned)t &&
             ++guard < 1000000)
        __builtin_amdgcn_s_sleep(1);
    }
    __builtin_amdgcn_sched_barrier(0);  // keep data loads below the spin

    // prefetch next step's u (consumed next iteration; latency hides here)
    int tn = (t + 1 < T_DIM) ? t + 1 : t;
    f4_t unext = *(const f4_t*)(act + ((size_t)tn * B_DIM + b0 + pr) * H_DIM + h0 + pc);

    const unsigned short* hprev = hb[(t + 1) & 1];
    bf8_t Af[8];
#pragma unroll
    for (int kc = 0; kc < 8; ++kc) {
      const unsigned long long* ap =
          (const unsigned long long*)(hprev + (size_t)(b0 + lrow) * H_DIM + w * 256 +
                                      kc * 32 + lk);
      unsigned long long lo = __hip_atomic_load(ap, __ATOMIC_RELAXED, __HIP_MEMORY_SCOPE_AGENT);
      unsigned long long hi =
          __hip_atomic_load(ap + 1, __ATOMIC_RELAXED, __HIP_MEMORY_SCOPE_AGENT);
      union { unsigned long long q[2]; bf8_t v; } uu;
      uu.q[0] = lo;
      uu.q[1] = hi;
      Af[kc] = uu.v;
    }
    f4_t acc[4];
#pragma unroll
    for (int n = 0; n < 4; ++n) acc[n] = (f4_t){0.f, 0.f, 0.f, 0.f};
#pragma unroll
    for (int kc = 0; kc < 8; ++kc)
#pragma unroll
      for (int n = 0; n < 4; ++n)
        acc[n] = __builtin_amdgcn_mfma_f32_16x16x32_bf16(Af[kc], Bf[n][kc], acc[n], 0, 0, 0);

    // cross-wave K reduction via LDS
#pragma unroll
    for (int n = 0; n < 4; ++n)
#pragma unroll
      for (int r = 0; r < 4; ++r)
        pbuf[w][(lane >> 4) * 4 + r][n * 16 + lrow] = acc[n][r];
    __syncthreads();  // pbuf ready

    // pointwise: sum partials + u_t + bh, leaky update, relu
    f4_t hres;
#pragma unroll
    for (int j = 0; j < 4; ++j) {
      float tot = pbuf[0][pr][pc + j] + pbuf[1][pr][pc + j] + pbuf[2][pr][pc + j] +
                  pbuf[3][pr][pc + j] + ucur[j] + bh4[j];
      st[j] = st[j] * 0.8f + tot * 0.2f;
      hres[j] = fmaxf(st[j], 0.f);
    }
    *(f4_t*)(act + ((size_t)t * B_DIM + b0 + pr) * H_DIM + h0 + pc) = hres;
    unsigned long long hp = pack4bf(hres);
    __hip_atomic_store(
        (unsigned long long*)(hb[t & 1] + ((size_t)(b0 + pr)) * H_DIM + h0 + pc), hp,
        __ATOMIC_RELAXED, __HIP_MEMORY_SCOPE_AGENT);

    ucur = unext;

    __syncthreads();  // vmcnt(0) drain: pbuf WAR + all stores ack'd at IC
    if (tid == 0)
      __hip_atomic_store(myslot, (unsigned)(t + 1), __ATOMIC_RELAXED,
                         __HIP_MEMORY_SCOPE_AGENT);  // manual release (no wbl2)
  }
}

// ------------------------------------------------- phase 3: act @ Wo^T + bo -
__global__ __launch_bounds__(256, 2) void k_outproj(
    const float* __restrict__ act, const unsigned short* __restrict__ Wo_b,
    const float* __restrict__ bo, float* __restrict__ out) {
  __shared__ unsigned short As[128 * 64];
  __shared__ unsigned short Bs[128 * 64];
  int m0 = blockIdx.x * 128;
  int tid = threadIdx.x;
  int lane = tid & 63, w = tid >> 6;
  int wm0 = (w & 1) * 64, wn0 = (w >> 1) * 64;
  int lrow = lane & 15, lk = (lane >> 4) * 8;
  f4_t acc[4][4];
#pragma unroll
  for (int a = 0; a < 4; ++a)
#pragma unroll
    for (int b = 0; b < 4; ++b) acc[a][b] = (f4_t){0.f, 0.f, 0.f, 0.f};

  for (int kb = 0; kb < 16; ++kb) {
    if (kb) __syncthreads();
#pragma unroll
    for (int it = 0; it < 8; ++it) {
      int c = it * 256 + tid;
      int row = c >> 4;
      int kc = (c & 15) * 4;
      f4_t v = *(const f4_t*)(act + (size_t)(m0 + row) * H_DIM + kb * 64 + kc);
      *(unsigned long long*)((char*)As + SWZ(row, row * 128 + kc * 2)) = pack4bf(v);
    }
    // Bs: 128 rows x 64 k = 8192 bf16 -> 4 its x 256 thr x 8 bf16
#pragma unroll
    for (int it = 0; it < 4; ++it) {
      int c = it * 256 + tid;
      int row = c >> 3;
      int k16 = c & 7;
      u32x4 v = *(const u32x4*)(Wo_b + (size_t)row * H_DIM + kb * 64 + k16 * 8);
      *(u32x4*)((char*)Bs + SWZ(row, row * 128 + k16 * 16)) = v;
    }
    __syncthreads();
#pragma unroll
    for (int ks = 0; ks < 2; ++ks) {
      bf8_t aF[4], bF[4];
#pragma unroll
      for (int mt = 0; mt < 4; ++mt) {
        int row = wm0 + mt * 16 + lrow;
        aF[mt] = *(const bf8_t*)((char*)As + SWZ(row, row * 128 + (ks * 32 + lk) * 2));
      }
#pragma unroll
      for (int nt = 0; nt < 4; ++nt) {
        int row = wn0 + nt * 16 + lrow;
        bF[nt] = *(const bf8_t*)((char*)Bs + SWZ(row, row * 128 + (ks * 32 + lk) * 2));
      }
#pragma unroll
      for (int mt = 0; mt < 4; ++mt)
#pragma unroll
        for (int nt = 0; nt < 4; ++nt)
          acc[mt][nt] =
              __builtin_amdgcn_mfma_f32_16x16x32_bf16(aF[mt], bF[nt], acc[mt][nt], 0, 0, 0);
    }
  }
#pragma unroll
  for (int nt = 0; nt < 4; ++nt) {
    int col = wn0 + nt * 16 + lrow;
    float bv = bo[col];
#pragma unroll
    for (int mt = 0; mt < 4; ++mt) {
      int rbase = m0 + wm0 + mt * 16 + (lane >> 4) * 4;
#pragma unroll
      for (int r = 0; r < 4; ++r)
        out[(size_t)(rbase + r) * O_DIM + col] = acc[mt][nt][r] + bv;
    }
  }
}

// ---------------------------------------------------------------------------
extern "C" void kernel_launch(void* const* d_in, const int* in_sizes, int n_in,
                              void* d_out, int out_size, void* d_ws, size_t ws_size,
                              hipStream_t stream) {
  const float* x  = (const float*)d_in[0];
  const float* Wi = (const float*)d_in[1];
  const float* bi = (const float*)d_in[2];
  const float* Wh = (const float*)d_in[3];
  const float* bh = (const float*)d_in[4];
  const float* Wo = (const float*)d_in[5];
  const float* bo = (const float*)d_in[6];

  float* out = (float*)d_out;                                  // [T,B,O]
  float* act = out + (size_t)T_DIM * B_DIM * O_DIM;            // [T,B,H]

  char* ws = (char*)d_ws;
  unsigned short* Wh_b  = (unsigned short*)(ws);                               // 2 MB
  unsigned short* Wi_b  = (unsigned short*)(ws + (2u << 20));                  // 512 KB
  unsigned short* Wo_b  = (unsigned short*)(ws + (2u << 20) + (512u << 10));   // 256 KB
  unsigned short* hbuf0 = (unsigned short*)(ws + (2u << 20) + (768u << 10));   // 512 KB
  unsigned short* hbuf1 = (unsigned short*)(ws + (2u << 20) + (1280u << 10));  // 512 KB
  unsigned* done        = (unsigned*)(ws + (2u << 20) + (1792u << 10));        // 32 KB

  k_init<<<1024, 256, 0, stream>>>(Wi, Wh, Wo, Wi_b, Wh_b, Wo_b, hbuf1, done);
  k_inproj<<<8192, 256, 0, stream>>>(x, Wi_b, bi, act);
  k_scan<<<256, 256, 0, stream>>>(Wh_b, bh, act, hbuf0, hbuf1, done);
  k_outproj<<<1024, 256, 0, stream>>>(act, Wo_b, bo, out);
}